// Round 5
// baseline (140.256 us; speedup 1.0000x reference)
//
#include <hip/hip_runtime.h>
#include <stdint.h>

#define NPAT 4096
#define DIM  256
#define KB   1024       // bytes per patient row: 4 modalities * 256 fp8
#define EPSV 1e-8f
#define BT   128        // block tile (M and N); wave tile 64x64
#define NT   (NPAT / BT)            // 32 tiles per dim
#define NBLK (NT * (NT + 1) / 2)    // 528 upper-triangle blocks
#define NBINS 4096

typedef float f32x4 __attribute__((ext_vector_type(4)));
typedef long  lng2  __attribute__((ext_vector_type(2)));

// ---- workspace layout (bytes) ----
// [0..256): float scalars: [0]=sim_sum, [1]=cox n/d
#define WS_DVAL_OFF 256                          // float4[NPAT]
#define WS_MVEC_OFF (WS_DVAL_OFF + 16*NPAT)      // float4[NPAT]
#define WS_XN_OFF   (WS_MVEC_OFF + 16*NPAT)      // uint8[NPAT*KB] = 4 MB

__device__ __forceinline__ float decode_margin(const int* pm) {
  int v = *pm;
  if (v > -16777216 && v < 16777216) return (float)v;  // stored as int
  return __int_as_float(v);                            // stored as float bits
}

// ---------- prep: wave-per-(patient,modality); fp8 quantize; zero accumulator ----------
__global__ __launch_bounds__(256) void prep_kernel(
    const float4* __restrict__ eb0, const float4* __restrict__ eb1,
    const float4* __restrict__ eb2, const float4* __restrict__ eb3,
    uint8_t* __restrict__ Xn, float* __restrict__ dval_f,
    float* __restrict__ mvec_f, float* __restrict__ scal)
{
  const int i    = blockIdx.x;
  const int wv   = threadIdx.x >> 6;   // modality
  const int lane = threadIdx.x & 63;
  const float4* ebs[4] = {eb0, eb1, eb2, eb3};
  const float4 v = ebs[wv][i * (DIM / 4) + lane];
  float s = v.x * v.x + v.y * v.y + v.z * v.z + v.w * v.w;
#pragma unroll
  for (int o = 32; o; o >>= 1) s += __shfl_down(s, o, 64);
  s = __shfl(s, 0, 64);
  const float x0 = __shfl(v.x, 0, 64);
  const bool eq = (v.x == x0) && (v.y == x0) && (v.z == x0) && (v.w == x0);
  const bool miss = (__ballot(eq) == ~0ull);
  const float nrm = sqrtf(s);
  const float den = fmaxf(nrm, EPSV);
  const float inv = miss ? 0.0f : (1.0f / den);
  int p = 0;
  p = __builtin_amdgcn_cvt_pk_fp8_f32(v.x * inv, v.y * inv, p, false);
  p = __builtin_amdgcn_cvt_pk_fp8_f32(v.z * inv, v.w * inv, p, true);
  *(int*)&Xn[(size_t)i * KB + wv * DIM + lane * 4] = p;
  if (lane == 0) {
    const float diag = (nrm * nrm) / (den * den);
    dval_f[i * 4 + wv] = miss ? 0.0f : diag;
    mvec_f[i * 4 + wv] = miss ? 0.0f : 1.0f;
  }
  if (i == 0 && threadIdx.x == 0) scal[0] = 0.0f;  // zero sim accumulator
}

// ---------- similarity GEMM: no LDS in K-loop, fragments streamed from L2 ----------
__global__ __launch_bounds__(256, 4) void sim_gemm_kernel(
    const uint8_t* __restrict__ Xn, const float4* __restrict__ dval,
    const float4* __restrict__ mvec, const int* __restrict__ pmargin,
    float* __restrict__ sim_acc)
{
  __shared__ float4 eRDi[BT], eCMi[BT], eRDj[BT], eCMj[BT];  // 8 KB epilogue stage
  __shared__ float  wred[4];

  // linear -> (bi, bj) upper triangle, row-major
  const int L = blockIdx.x;
  int bi = (int)((2 * NT + 1 - sqrtf((float)((2 * NT + 1) * (2 * NT + 1)) - 8.0f * L)) * 0.5f);
  if (bi < 0) bi = 0;
  if (bi > NT - 1) bi = NT - 1;
  while (bi > 0 && bi * NT - bi * (bi - 1) / 2 > L) --bi;
  while ((bi + 1) * NT - (bi + 1) * bi / 2 <= L) ++bi;
  const int bj = bi + (L - (bi * NT - bi * (bi - 1) / 2));

  const int tid = threadIdx.x;
  const int lane = tid & 63, wvv = tid >> 6;
  const int wi = wvv >> 1, wj = wvv & 1;
  const int mrow = lane & 15, kg = lane >> 4;

  // Per-lane 16B loads: row-major fp8, lanes kg=0..3 of a row cover one 64B line.
  // k-permutation-invariant: halves of the 16B feed 2 MFMAs with identical
  // lane->k maps on A and B, so the sum over all steps is the exact dot.
  const uint8_t* pA[4];
  const uint8_t* pB[4];
#pragma unroll
  for (int mi = 0; mi < 4; ++mi)
    pA[mi] = Xn + (size_t)(bi * BT + wi * 64 + mi * 16 + mrow) * KB + kg * 16;
#pragma unroll
  for (int mj = 0; mj < 4; ++mj)
    pB[mj] = Xn + (size_t)(bj * BT + wj * 64 + mj * 16 + mrow) * KB + kg * 16;

  f32x4 acc[4][4] = {};

#pragma unroll
  for (int ks = 0; ks < 16; ++ks) {           // 16 macro-steps x 64B of K
    lng2 af[4], bf[4];
#pragma unroll
    for (int mi = 0; mi < 4; ++mi) af[mi] = *(const lng2*)(pA[mi] + ks * 64);
#pragma unroll
    for (int mj = 0; mj < 4; ++mj) bf[mj] = *(const lng2*)(pB[mj] + ks * 64);
#pragma unroll
    for (int h = 0; h < 2; ++h)
#pragma unroll
      for (int mi = 0; mi < 4; ++mi)
#pragma unroll
        for (int mj = 0; mj < 4; ++mj)
          acc[mi][mj] = __builtin_amdgcn_mfma_f32_16x16x32_fp8_fp8(
              af[mi][h], bf[mj][h], acc[mi][mj], 0, 0, 0);
  }

  // epilogue
  if (tid < BT) {
    eRDi[tid] = dval[bi * BT + tid];
    eCMi[tid] = mvec[bi * BT + tid];
  } else {
    const int s = tid - BT;
    eRDj[s] = dval[bj * BT + s];
    eCMj[s] = mvec[bj * BT + s];
  }
  __syncthreads();

  const float margin = decode_margin(pmargin);
  const bool isDiag = (bi == bj);
  float local = 0.0f;
  const int rq = (lane >> 4) * 4;                  // C/D: row=(lane>>4)*4+reg
  const int cc = lane & 15;                        //      col=lane&15
#pragma unroll
  for (int mi = 0; mi < 4; ++mi) {
#pragma unroll
    for (int mj = 0; mj < 4; ++mj) {
      const int jl = wj * 64 + mj * 16 + cc;
      const float4 cmj = eCMj[jl];
      const float4 rdj = eRDj[jl];
#pragma unroll
      for (int r = 0; r < 4; ++r) {
        const int il = wi * 64 + mi * 16 + rq + r;
        const float4 rdi = eRDi[il];
        const float sv = acc[mi][mj][r];
        const float own_ij = rdi.x * cmj.x + rdi.y * cmj.y + rdi.z * cmj.z + rdi.w * cmj.w;
        const float v1 = fmaxf(margin - sv + own_ij, 0.0f);
        local += (isDiag && il == jl) ? 0.0f : v1;
        if (!isDiag) {                             // transposed pair (j,i)
          const float4 cmi = eCMi[il];
          const float own_ji = rdj.x * cmi.x + rdj.y * cmi.y + rdj.z * cmi.z + rdj.w * cmi.w;
          local += fmaxf(margin - sv + own_ji, 0.0f);
        }
      }
    }
  }
#pragma unroll
  for (int o = 32; o; o >>= 1) local += __shfl_down(local, o, 64);
  if (lane == 0) wred[wvv] = local;
  __syncthreads();
  if (tid == 0) atomicAdd(sim_acc, wred[0] + wred[1] + wred[2] + wred[3]);
}

// ---------- Cox: histogram + suffix-scan + NPLL; writes scal[1] = n/d ----------
__global__ __launch_bounds__(1024) void cox_kernel(
    const float* __restrict__ h, const int* __restrict__ t,
    const int* __restrict__ e, float* __restrict__ scal)
{
  __shared__ float bins[NBINS];
  __shared__ float p[1024];
  __shared__ float rn[16], rd[16];
  const int tid = threadIdx.x;
#pragma unroll
  for (int k = 0; k < 4; ++k) bins[tid + k * 1024] = 0.0f;
  __syncthreads();
#pragma unroll
  for (int k = 0; k < 4; ++k) {
    const int i = tid + k * 1024;
    atomicAdd(&bins[t[i]], expf(h[i]));
  }
  __syncthreads();
  const float b0 = bins[4 * tid], b1 = bins[4 * tid + 1];
  const float b2 = bins[4 * tid + 2], b3 = bins[4 * tid + 3];
  const float part = b0 + b1 + b2 + b3;
  p[tid] = part;
  __syncthreads();
  for (int off = 1; off < 1024; off <<= 1) {
    const float v = p[tid];
    const float a = (tid + off < 1024) ? p[tid + off] : 0.0f;
    __syncthreads();
    p[tid] = v + a;
    __syncthreads();
  }
  const float above = p[tid] - part;
  const float s3 = above + b3, s2 = s3 + b2, s1 = s2 + b1, s0 = s1 + b0;
  bins[4 * tid] = s0; bins[4 * tid + 1] = s1;
  bins[4 * tid + 2] = s2; bins[4 * tid + 3] = s3;
  __syncthreads();
  float nloc = 0.0f, dloc = 0.0f;
#pragma unroll
  for (int k = 0; k < 4; ++k) {
    const int i = tid + k * 1024;
    const float ei = (float)e[i];
    if (ei != 0.0f) { nloc += ei * (h[i] - logf(bins[t[i]])); dloc += ei; }
  }
  const int lane = tid & 63, w = tid >> 6;
#pragma unroll
  for (int o = 32; o; o >>= 1) {
    nloc += __shfl_down(nloc, o, 64);
    dloc += __shfl_down(dloc, o, 64);
  }
  if (lane == 0) { rn[w] = nloc; rd[w] = dloc; }
  __syncthreads();
  if (tid == 0) {
    float n = 0.0f, d = 0.0f;
#pragma unroll
    for (int k = 0; k < 16; ++k) { n += rn[k]; d += rd[k]; }
    scal[1] = n / d;
  }
}

__global__ void finalize_kernel(const float* __restrict__ scal, float* __restrict__ out) {
  out[0] = scal[0] - scal[1];   // sim + cox (cox = -n/d)
}

extern "C" void kernel_launch(void* const* d_in, const int* in_sizes, int n_in,
                              void* d_out, int out_size, void* d_ws, size_t ws_size,
                              hipStream_t stream) {
  const float* h    = (const float*)d_in[0];
  const int*   t    = (const int*)  d_in[1];
  const int*   e    = (const int*)  d_in[2];
  const float4* eb0 = (const float4*)d_in[3];
  const float4* eb1 = (const float4*)d_in[4];
  const float4* eb2 = (const float4*)d_in[5];
  const float4* eb3 = (const float4*)d_in[6];
  const int*   pm   = (const int*)  d_in[7];

  char*    ws   = (char*)d_ws;
  float*   scal = (float*)ws;
  float*   dvf  = (float*)(ws + WS_DVAL_OFF);
  float*   mvf  = (float*)(ws + WS_MVEC_OFF);
  uint8_t* Xn   = (uint8_t*)(ws + WS_XN_OFF);

  prep_kernel<<<NPAT, 256, 0, stream>>>(eb0, eb1, eb2, eb3, Xn, dvf, mvf, scal);
  cox_kernel<<<1, 1024, 0, stream>>>(h, t, e, scal);           // overlaps with sim
  sim_gemm_kernel<<<NBLK, 256, 0, stream>>>(Xn, (const float4*)dvf, (const float4*)mvf, pm, &scal[0]);
  finalize_kernel<<<1, 1, 0, stream>>>(scal, (float*)d_out);
}

// Round 6
// 121.094 us; speedup vs baseline: 1.1582x; 1.1582x over previous
//
#include <hip/hip_runtime.h>
#include <stdint.h>

#define NPAT 4096
#define DIM  256
#define KB   1024       // bytes per patient row: 4 modalities * 256 fp8
#define EPSV 1e-8f
#define BT   128        // block tile (M and N)
#define BKB  256        // K-bytes per staging iter (8 MFMA k-steps of 32B)
#define NT   (NPAT / BT)            // 32 tiles per dim
#define NBLK (NT * (NT + 1) / 2)    // 528 upper-triangle blocks
#define NBINS 4096

typedef float f32x4 __attribute__((ext_vector_type(4)));

// ---- workspace layout (bytes) ----
// [0..256): scalars: f[0]=sim_sum, f[1]=cox n/d, u[2]=ticket
#define WS_DVAL_OFF 256                          // float4[NPAT]
#define WS_MVEC_OFF (WS_DVAL_OFF + 16*NPAT)      // float4[NPAT]
#define WS_XN_OFF   (WS_MVEC_OFF + 16*NPAT)      // uint8[NPAT*KB] = 4 MB

__device__ __forceinline__ void gl_lds16(const uint8_t* g, uint8_t* l) {
  __builtin_amdgcn_global_load_lds(
      (const __attribute__((address_space(1))) void*)g,
      (__attribute__((address_space(3))) void*)l, 16, 0, 0);
}

__device__ __forceinline__ float decode_margin(const int* pm) {
  int v = *pm;
  if (v > -16777216 && v < 16777216) return (float)v;  // stored as int
  return __int_as_float(v);                            // stored as float bits
}

// ---------- prep: wave-per-(patient,modality); fp8 quantize; zero scalars ----------
__global__ __launch_bounds__(256) void prep_kernel(
    const float4* __restrict__ eb0, const float4* __restrict__ eb1,
    const float4* __restrict__ eb2, const float4* __restrict__ eb3,
    uint8_t* __restrict__ Xn, float* __restrict__ dval_f,
    float* __restrict__ mvec_f, float* __restrict__ scal)
{
  const int i    = blockIdx.x;
  const int wv   = threadIdx.x >> 6;   // modality
  const int lane = threadIdx.x & 63;
  const float4* ebs[4] = {eb0, eb1, eb2, eb3};
  const float4 v = ebs[wv][i * (DIM / 4) + lane];
  float s = v.x * v.x + v.y * v.y + v.z * v.z + v.w * v.w;
#pragma unroll
  for (int o = 32; o; o >>= 1) s += __shfl_down(s, o, 64);
  s = __shfl(s, 0, 64);
  const float x0 = __shfl(v.x, 0, 64);
  const bool eq = (v.x == x0) && (v.y == x0) && (v.z == x0) && (v.w == x0);
  const bool miss = (__ballot(eq) == ~0ull);
  const float nrm = sqrtf(s);
  const float den = fmaxf(nrm, EPSV);
  const float inv = miss ? 0.0f : (1.0f / den);
  int p = 0;
  p = __builtin_amdgcn_cvt_pk_fp8_f32(v.x * inv, v.y * inv, p, false);
  p = __builtin_amdgcn_cvt_pk_fp8_f32(v.z * inv, v.w * inv, p, true);
  *(int*)&Xn[(size_t)i * KB + wv * DIM + lane * 4] = p;
  if (lane == 0) {
    const float diag = (nrm * nrm) / (den * den);
    dval_f[i * 4 + wv] = miss ? 0.0f : diag;
    mvec_f[i * 4 + wv] = miss ? 0.0f : 1.0f;
  }
  if (i == 0 && threadIdx.x == 0) {
    scal[0] = 0.0f;                    // sim accumulator
    scal[1] = 0.0f;                    // cox n/d
    ((unsigned*)scal)[2] = 0u;         // ticket
  }
}

// ---------- fused: sim GEMM (blocks 0..NBLK-1) + cox (block NBLK) + finalize ----------
__global__ __launch_bounds__(512, 4) void sim_gemm_kernel(
    const uint8_t* __restrict__ Xn, const float4* __restrict__ dval,
    const float4* __restrict__ mvec, const int* __restrict__ pmargin,
    const float* __restrict__ h, const int* __restrict__ t,
    const int* __restrict__ e, float* __restrict__ scal,
    float* __restrict__ out)
{
  __shared__ __align__(16) uint8_t smem[2 * BT * BKB];   // 64 KB (lA | lB), aliased below
  __shared__ float wred[8];
  uint8_t* lA = smem;
  uint8_t* lB = smem + BT * BKB;

  const int L   = blockIdx.x;
  const int tid = threadIdx.x;
  const int lane = tid & 63, wvv = tid >> 6;

  if (L == NBLK) {
    // ================= Cox path (512 threads) =================
    float* bins = (float*)smem;                 // 16 KB
    float* wt   = (float*)(smem + 16384);       // 8 floats
    float* rn   = (float*)(smem + 16384 + 64);
    float* rd   = (float*)(smem + 16384 + 128);
#pragma unroll
    for (int k = 0; k < 8; ++k) bins[tid + k * 512] = 0.0f;
    __syncthreads();
#pragma unroll
    for (int k = 0; k < 8; ++k) {
      const int i = tid + k * 512;
      atomicAdd(&bins[t[i]], expf(h[i]));
    }
    __syncthreads();
    // suffix scan: bins[b] <- sum_{v>=b} bins[v]; thread owns bins[8t..8t+7]
    float seg[8]; float part = 0.0f;
#pragma unroll
    for (int k = 0; k < 8; ++k) { seg[k] = bins[tid * 8 + k]; part += seg[k]; }
    float sfx = part;                           // inclusive suffix within wave
#pragma unroll
    for (int off = 1; off < 64; off <<= 1) {
      const float u = __shfl_down(sfx, off, 64);
      if (lane + off < 64) sfx += u;
    }
    if (lane == 0) wt[wvv] = sfx;               // wave totals
    __syncthreads();
    float above = 0.0f;
    for (int w = wvv + 1; w < 8; ++w) above += wt[w];
    float run = above + (sfx - part);           // strictly-after my segment
#pragma unroll
    for (int k = 7; k >= 0; --k) { run += seg[k]; bins[tid * 8 + k] = run; }
    __syncthreads();
    float nloc = 0.0f, dloc = 0.0f;
#pragma unroll
    for (int k = 0; k < 8; ++k) {
      const int i = tid + k * 512;
      const float ei = (float)e[i];
      if (ei != 0.0f) { nloc += ei * (h[i] - logf(bins[t[i]])); dloc += ei; }
    }
#pragma unroll
    for (int o = 32; o; o >>= 1) {
      nloc += __shfl_down(nloc, o, 64);
      dloc += __shfl_down(dloc, o, 64);
    }
    if (lane == 0) { rn[wvv] = nloc; rd[wvv] = dloc; }
    __syncthreads();
    if (tid == 0) {
      float n = 0.0f, d = 0.0f;
#pragma unroll
      for (int k = 0; k < 8; ++k) { n += rn[k]; d += rd[k]; }
      atomicExch(&scal[1], n / d);              // L2-coherent publish
      __threadfence();
      const unsigned old = atomicAdd(&((unsigned*)scal)[2], 1u);
      if (old == NBLK) {                        // last of NBLK+1 blocks
        __threadfence();
        out[0] = atomicAdd(&scal[0], 0.0f) - (n / d);
      }
    }
    return;
  }

  // ================= GEMM path =================
  // linear -> (bi, bj) upper triangle, row-major
  int bi = (int)((2 * NT + 1 - sqrtf((float)((2 * NT + 1) * (2 * NT + 1)) - 8.0f * L)) * 0.5f);
  if (bi < 0) bi = 0;
  if (bi > NT - 1) bi = NT - 1;
  while (bi > 0 && bi * NT - bi * (bi - 1) / 2 > L) --bi;
  while ((bi + 1) * NT - (bi + 1) * bi / 2 <= L) ++bi;
  const int bj = bi + (L - (bi * NT - bi * (bi - 1) / 2));

  const int wi = wvv >> 1, wj = wvv & 1;        // wave tile: rows 32*wi, cols 64*wj
  const int mrow = lane & 15, kg = lane >> 4;
  const int kgh = kg >> 1, half8 = (kg & 1) * 8;

  // staging: thread stages 16B. XOR swizzle at 16B granularity:
  // LDS[row][slot] = global[row][slot ^ (row&15)] -> readers conflict-free (2-way max)
  const int srow   = tid >> 4;                  // 0..31 per q-call
  const int sgoff  = ((tid & 15) ^ (srow & 15)) * 16;
  const uint8_t* gA = Xn + (size_t)(bi * BT) * KB;
  const uint8_t* gB = Xn + (size_t)(bj * BT) * KB;

  f32x4 acc[2][4] = {};                         // 2 row-frags x 4 col-frags (64x32 per wave)
  const int rA0 = wi * 32 + mrow;
  const int rB0 = wj * 64 + mrow;

  for (int kit = 0; kit < 4; ++kit) {
    const int k0 = kit * BKB;
    __syncthreads();
#pragma unroll
    for (int q = 0; q < 4; ++q) {               // 4 calls x 8KB per tile
      const size_t go = (size_t)(q * 32 + srow) * KB + k0 + sgoff;
      gl_lds16(gA + go, &lA[q * 8192 + tid * 16]);
      gl_lds16(gB + go, &lB[q * 8192 + tid * 16]);
    }
    __syncthreads();                            // drains vmcnt before barrier
#pragma unroll
    for (int s = 0; s < 8; ++s) {
      const int o = (((2 * s + kgh) ^ mrow) << 4) + half8;
      const long a0 = *(const long*)&lA[(rA0)      * BKB + o];
      const long a1 = *(const long*)&lA[(rA0 + 16) * BKB + o];
      long bf[4];
#pragma unroll
      for (int mj = 0; mj < 4; ++mj) bf[mj] = *(const long*)&lB[(rB0 + mj * 16) * BKB + o];
#pragma unroll
      for (int mj = 0; mj < 4; ++mj) {
        acc[0][mj] = __builtin_amdgcn_mfma_f32_16x16x32_fp8_fp8(a0, bf[mj], acc[0][mj], 0, 0, 0);
        acc[1][mj] = __builtin_amdgcn_mfma_f32_16x16x32_fp8_fp8(a1, bf[mj], acc[1][mj], 0, 0, 0);
      }
    }
  }

  // epilogue: alias dval/mvec staging onto smem (tiles no longer needed)
  __syncthreads();
  float4* eRDi = (float4*)smem;
  float4* eCMi = (float4*)smem + BT;
  float4* eRDj = (float4*)smem + 2 * BT;
  float4* eCMj = (float4*)smem + 3 * BT;
  if (tid < BT) {
    eRDi[tid] = dval[bi * BT + tid];
    eCMi[tid] = mvec[bi * BT + tid];
  } else if (tid < 2 * BT) {
    const int s = tid - BT;
    eRDj[s] = dval[bj * BT + s];
    eCMj[s] = mvec[bj * BT + s];
  }
  __syncthreads();

  const float margin = decode_margin(pmargin);
  const bool isDiag = (bi == bj);
  float local = 0.0f;
  const int rq = (lane >> 4) * 4;               // C/D: row=(lane>>4)*4+reg
  const int cc = lane & 15;                     //      col=lane&15
#pragma unroll
  for (int mi = 0; mi < 2; ++mi) {
#pragma unroll
    for (int mj = 0; mj < 4; ++mj) {
      const int jl = wj * 64 + mj * 16 + cc;
      const float4 cmj = eCMj[jl];
      const float4 rdj = eRDj[jl];
#pragma unroll
      for (int r = 0; r < 4; ++r) {
        const int il = wi * 32 + mi * 16 + rq + r;
        const float4 rdi = eRDi[il];
        const float sv = acc[mi][mj][r];
        const float own_ij = rdi.x * cmj.x + rdi.y * cmj.y + rdi.z * cmj.z + rdi.w * cmj.w;
        const float v1 = fmaxf(margin - sv + own_ij, 0.0f);
        local += (isDiag && il == jl) ? 0.0f : v1;
        if (!isDiag) {                          // transposed pair (j,i)
          const float4 cmi = eCMi[il];
          const float own_ji = rdj.x * cmi.x + rdj.y * cmi.y + rdj.z * cmi.z + rdj.w * cmi.w;
          local += fmaxf(margin - sv + own_ji, 0.0f);
        }
      }
    }
  }
#pragma unroll
  for (int o = 32; o; o >>= 1) local += __shfl_down(local, o, 64);
  if (lane == 0) wred[wvv] = local;
  __syncthreads();
  if (tid == 0) {
    float bsum = 0.0f;
#pragma unroll
    for (int k = 0; k < 8; ++k) bsum += wred[k];
    atomicAdd(&scal[0], bsum);
    __threadfence();
    const unsigned old = atomicAdd(&((unsigned*)scal)[2], 1u);
    if (old == NBLK) {                          // last of NBLK+1 blocks
      __threadfence();
      out[0] = atomicAdd(&scal[0], 0.0f) - atomicAdd(&scal[1], 0.0f);
    }
  }
}

extern "C" void kernel_launch(void* const* d_in, const int* in_sizes, int n_in,
                              void* d_out, int out_size, void* d_ws, size_t ws_size,
                              hipStream_t stream) {
  const float* h    = (const float*)d_in[0];
  const int*   t    = (const int*)  d_in[1];
  const int*   e    = (const int*)  d_in[2];
  const float4* eb0 = (const float4*)d_in[3];
  const float4* eb1 = (const float4*)d_in[4];
  const float4* eb2 = (const float4*)d_in[5];
  const float4* eb3 = (const float4*)d_in[6];
  const int*   pm   = (const int*)  d_in[7];

  char*    ws   = (char*)d_ws;
  float*   scal = (float*)ws;
  float*   dvf  = (float*)(ws + WS_DVAL_OFF);
  float*   mvf  = (float*)(ws + WS_MVEC_OFF);
  uint8_t* Xn   = (uint8_t*)(ws + WS_XN_OFF);

  prep_kernel<<<NPAT, 256, 0, stream>>>(eb0, eb1, eb2, eb3, Xn, dvf, mvf, scal);
  sim_gemm_kernel<<<NBLK + 1, 512, 0, stream>>>(Xn, (const float4*)dvf, (const float4*)mvf,
                                                pm, h, t, e, scal, (float*)d_out);
}